// Round 1
// baseline (357.474 us; speedup 1.0000x reference)
//
#include <hip/hip_runtime.h>
#include <hip/hip_bf16.h>
#include <math.h>

// Problem constants (B=1, LAYERS=33, HEADS=20, SEQ=512)
#define SEQ   512
#define NF    660           // 33*20
#define CROP  510           // SEQ-2
#define EOSI  2

// ---------------- Pass 1: stream 692MB once ----------------
// grid (32 row-tiles, 33 head-groups), block 256 (4 waves)
// Each block: rows [t*16, t*16+16) x all 512 cols x heads [g*20, g*20+20)
// Outputs: WA[512][512] (+= w_f * A_f, atomics), rowsum[f][i] (exact, no atomic),
//          colsum[f][j] (+= partial over 16 rows, atomics)
#define RT 16   // rows per block
#define GH 20   // heads per group

__global__ __launch_bounds__(256) void pass1_kernel(
    const float* __restrict__ A, const int* __restrict__ tokens,
    const float* __restrict__ weight,
    float* __restrict__ WA, float* __restrict__ rowsum, float* __restrict__ colsum)
{
    __shared__ float msk[SEQ];
    __shared__ float col_lds[4][SEQ];

    const int t   = blockIdx.x;          // row tile
    const int g   = blockIdx.y;          // head group
    const int tid = threadIdx.x;
    const int wave = tid >> 6;
    const int lane = tid & 63;

    // crop+eos mask over full index space
    for (int j = tid; j < SEQ; j += 256)
        msk[j] = (j >= 1 && j <= SEQ - 2 && tokens[j] != EOSI) ? 1.0f : 0.0f;
    __syncthreads();

    // fixed column ownership per thread: e in 0..7 -> col = (e>>2)*256 + 4*lane + (e&3)
    float mskv[8];
    #pragma unroll
    for (int e = 0; e < 8; ++e) {
        int col = (e >> 2) * 256 + 4 * lane + (e & 3);
        mskv[e] = msk[col];
    }

    const int row0 = t * RT + wave * 4;  // this wave's 4 rows

    float wa_acc[4][8];
    #pragma unroll
    for (int r = 0; r < 4; ++r)
        #pragma unroll
        for (int e = 0; e < 8; ++e) wa_acc[r][e] = 0.0f;

    for (int fg = 0; fg < GH; ++fg) {
        const int f = g * GH + fg;
        const float wf = weight[f];
        const float* __restrict__ Af = A + (size_t)f * SEQ * SEQ;

        float colacc[8];
        #pragma unroll
        for (int e = 0; e < 8; ++e) colacc[e] = 0.0f;

        #pragma unroll
        for (int rr = 0; rr < 4; ++rr) {
            const int i = row0 + rr;
            const float* __restrict__ rowp = Af + (size_t)i * SEQ;
            float4 v0 = *(const float4*)(rowp + 4 * lane);
            float4 v1 = *(const float4*)(rowp + 256 + 4 * lane);
            float vals[8] = {v0.x, v0.y, v0.z, v0.w, v1.x, v1.y, v1.z, v1.w};
            const float mi = msk[i];
            float rsum = 0.0f;
            #pragma unroll
            for (int e = 0; e < 8; ++e) {
                const float v = vals[e];
                wa_acc[rr][e] += wf * v;
                rsum += mskv[e] * v;
                colacc[e] += mi * v;
            }
            // wave-wide (64-lane) reduce of masked row sum
            #pragma unroll
            for (int off = 32; off > 0; off >>= 1)
                rsum += __shfl_down(rsum, off, 64);
            if (lane == 0) rowsum[(size_t)f * SEQ + i] = rsum;
        }

        // combine per-wave colsum partials across the 4 waves via LDS
        #pragma unroll
        for (int e = 0; e < 8; ++e) {
            int col = (e >> 2) * 256 + 4 * lane + (e & 3);
            col_lds[wave][col] = colacc[e];
        }
        __syncthreads();
        for (int j = tid; j < SEQ; j += 256) {
            float s = col_lds[0][j] + col_lds[1][j] + col_lds[2][j] + col_lds[3][j];
            atomicAdd(&colsum[(size_t)f * SEQ + j], s);
        }
        __syncthreads();
    }

    // flush WA accumulators (amortized over 20 heads)
    #pragma unroll
    for (int rr = 0; rr < 4; ++rr) {
        const int i = row0 + rr;
        #pragma unroll
        for (int e = 0; e < 8; ++e) {
            int col = (e >> 2) * 256 + 4 * lane + (e & 3);
            atomicAdd(&WA[(size_t)i * SEQ + col], wa_acc[rr][e]);
        }
    }
}

// ---------------- Pass 2: per-head a1, a12, scale ----------------
// grid 660, block 512
__global__ __launch_bounds__(512) void pass2_kernel(
    const float* __restrict__ rowsum, const float* __restrict__ colsum,
    const int* __restrict__ tokens, const float* __restrict__ weight,
    float* __restrict__ a1, float* __restrict__ sfac)
{
    const int f = blockIdx.x;
    const int j = threadIdx.x;
    const int wave = j >> 6, lane = j & 63;

    const float m = (j >= 1 && j <= SEQ - 2 && tokens[j] != EOSI) ? 1.0f : 0.0f;
    float v = m * (rowsum[(size_t)f * SEQ + j] + colsum[(size_t)f * SEQ + j]);
    a1[(size_t)f * SEQ + j] = v;

    // block reduce -> a12
    float s = v;
    #pragma unroll
    for (int off = 32; off > 0; off >>= 1)
        s += __shfl_down(s, off, 64);
    __shared__ float part[8];
    if (lane == 0) part[wave] = s;
    __syncthreads();
    if (j == 0) {
        float a12 = 0.0f;
        #pragma unroll
        for (int k = 0; k < 8; ++k) a12 += part[k];
        sfac[f] = weight[f] / a12;
    }
}

// ---------------- Pass 3: rank-660 outer-product sum + WA + sigmoid ----------------
// grid (16,16), block 256; each block: 32x32 output tile; thread: 2x2 micro-tile
__global__ __launch_bounds__(256) void pass3_kernel(
    const float* __restrict__ WA, const float* __restrict__ a1,
    const float* __restrict__ sfac, const int* __restrict__ tokens,
    const float* __restrict__ bias, float* __restrict__ out)
{
    const int TI = blockIdx.y * 32;   // cropped-row tile base
    const int TJ = blockIdx.x * 32;   // cropped-col tile base
    const int tid = threadIdx.x;
    const int tx = tid & 15, ty = tid >> 4;

    __shared__ float u_s[16][33];     // f-chunk x I-tile (scaled by sfac)
    __shared__ float v_s[16][33];     // f-chunk x J-tile

    float acc[2][2] = {{0.f, 0.f}, {0.f, 0.f}};

    for (int f0 = 0; f0 < NF; f0 += 16) {
        for (int e = tid; e < 512; e += 256) {
            const int ff = e >> 5, ii = e & 31;
            const int f = f0 + ff;
            int Iu = TI + 1 + ii; if (Iu > SEQ - 1) Iu = SEQ - 1;
            int Ju = TJ + 1 + ii; if (Ju > SEQ - 1) Ju = SEQ - 1;
            if (f < NF) {
                u_s[ff][ii] = a1[(size_t)f * SEQ + Iu] * sfac[f];
                v_s[ff][ii] = a1[(size_t)f * SEQ + Ju];
            } else {
                u_s[ff][ii] = 0.0f;
                v_s[ff][ii] = 0.0f;
            }
        }
        __syncthreads();
        #pragma unroll
        for (int ff = 0; ff < 16; ++ff) {
            const float u0 = u_s[ff][2 * ty],     u1 = u_s[ff][2 * ty + 1];
            const float w0 = v_s[ff][2 * tx],     w1 = v_s[ff][2 * tx + 1];
            acc[0][0] += u0 * w0; acc[0][1] += u0 * w1;
            acc[1][0] += u1 * w0; acc[1][1] += u1 * w1;
        }
        __syncthreads();
    }

    const float b = bias[0];
    #pragma unroll
    for (int dy = 0; dy < 2; ++dy) {
        #pragma unroll
        for (int dx = 0; dx < 2; ++dx) {
            const int i = TI + 2 * ty + dy;
            const int j = TJ + 2 * tx + dx;
            if (i < CROP && j < CROP) {
                const int I = i + 1, J = j + 1;
                const float mi = (tokens[I] != EOSI) ? 1.0f : 0.0f;
                const float mj = (tokens[J] != EOSI) ? 1.0f : 0.0f;
                const float first = mi * mj * (WA[(size_t)I * SEQ + J] + WA[(size_t)J * SEQ + I]);
                const float logit = first - acc[dy][dx] + b;
                out[(size_t)i * CROP + j] = 1.0f / (1.0f + expf(-logit));
            }
        }
    }
}

extern "C" void kernel_launch(void* const* d_in, const int* in_sizes, int n_in,
                              void* d_out, int out_size, void* d_ws, size_t ws_size,
                              hipStream_t stream) {
    const int*   tokens = (const int*)d_in[0];
    const float* A      = (const float*)d_in[1];
    const float* weight = (const float*)d_in[2];
    const float* bias   = (const float*)d_in[3];
    float* out = (float*)d_out;

    // workspace layout (floats): WA[512*512] | colsum[660*512] | rowsum[660*512] | a1[660*512] | sfac[660]
    float* WA     = (float*)d_ws;
    float* colsum = WA + (size_t)SEQ * SEQ;
    float* rowsum = colsum + (size_t)NF * SEQ;
    float* a1     = rowsum + (size_t)NF * SEQ;
    float* sfac   = a1 + (size_t)NF * SEQ;

    // zero the atomic-accumulated buffers (WA + colsum are adjacent)
    hipMemsetAsync(d_ws, 0, ((size_t)SEQ * SEQ + (size_t)NF * SEQ) * sizeof(float), stream);

    dim3 g1(SEQ / RT, NF / GH);          // 32 x 33
    pass1_kernel<<<g1, 256, 0, stream>>>(A, tokens, weight, WA, rowsum, colsum);

    pass2_kernel<<<NF, 512, 0, stream>>>(rowsum, colsum, tokens, weight, a1, sfac);

    dim3 g3(16, 16);
    pass3_kernel<<<g3, 256, 0, stream>>>(WA, a1, sfac, tokens, bias, out);
}

// Round 2
// 283.239 us; speedup vs baseline: 1.2621x; 1.2621x over previous
//
#include <hip/hip_runtime.h>
#include <hip/hip_bf16.h>
#include <math.h>

// Problem constants (B=1, LAYERS=33, HEADS=20, SEQ=512)
#define SEQ   512
#define NF    660           // 33*20
#define CROP  510           // SEQ-2
#define EOSI  2
#define RT    16            // rows per block (pass1)
#define GH    20            // heads per group (pass1)
#define NT    (SEQ / RT)    // 32 row tiles
#define NG    (NF / GH)     // 33 head groups

// ---------------- Pass 1: stream 692MB once, write-once outputs ----------------
// grid (32 row-tiles, 33 head-groups), block 256 (4 waves)
// Outputs (all written exactly once, no atomics, no pre-zero needed):
//   rowsum[f][i]            - exact masked row sums
//   colpart[t][f][j]        - column partial over this block's 16 rows
//   WApart[g][i][j]         - sum_{f in group g} w_f * A_f  (rows of tile t)
__global__ __launch_bounds__(256) void pass1_kernel(
    const float* __restrict__ A, const int* __restrict__ tokens,
    const float* __restrict__ weight,
    float* __restrict__ WApart, float* __restrict__ rowsum, float* __restrict__ colpart)
{
    __shared__ float msk[SEQ];
    __shared__ float col_lds[2][4][SEQ];   // ping-pong: 1 barrier per head

    const int t   = blockIdx.x;
    const int g   = blockIdx.y;
    const int tid = threadIdx.x;
    const int wave = tid >> 6;
    const int lane = tid & 63;

    for (int j = tid; j < SEQ; j += 256)
        msk[j] = (j >= 1 && j <= SEQ - 2 && tokens[j] != EOSI) ? 1.0f : 0.0f;
    __syncthreads();

    // fixed column ownership: e in 0..7 -> col = (e>>2)*256 + 4*lane + (e&3)
    float mskv[8];
    #pragma unroll
    for (int e = 0; e < 8; ++e)
        mskv[e] = msk[(e >> 2) * 256 + 4 * lane + (e & 3)];

    const int row0 = t * RT + wave * 4;    // this wave's 4 rows

    float wa_acc[4][8];
    #pragma unroll
    for (int r = 0; r < 4; ++r)
        #pragma unroll
        for (int e = 0; e < 8; ++e) wa_acc[r][e] = 0.0f;

    for (int fg = 0; fg < GH; ++fg) {
        const int f = g * GH + fg;
        const float wf = weight[f];
        const float* __restrict__ Af = A + (size_t)f * SEQ * SEQ;

        float colacc[8];
        #pragma unroll
        for (int e = 0; e < 8; ++e) colacc[e] = 0.0f;

        #pragma unroll
        for (int rr = 0; rr < 4; ++rr) {
            const int i = row0 + rr;
            const float* __restrict__ rowp = Af + (size_t)i * SEQ;
            float4 v0 = *(const float4*)(rowp + 4 * lane);
            float4 v1 = *(const float4*)(rowp + 256 + 4 * lane);
            float vals[8] = {v0.x, v0.y, v0.z, v0.w, v1.x, v1.y, v1.z, v1.w};
            const float mi = msk[i];
            float rsum = 0.0f;
            #pragma unroll
            for (int e = 0; e < 8; ++e) {
                const float v = vals[e];
                wa_acc[rr][e] += wf * v;
                rsum += mskv[e] * v;
                colacc[e] += mi * v;
            }
            #pragma unroll
            for (int off = 32; off > 0; off >>= 1)
                rsum += __shfl_down(rsum, off, 64);
            if (lane == 0) rowsum[(size_t)f * SEQ + i] = rsum;
        }

        // cross-wave colsum combine (ping-pong buffer, single barrier)
        const int ph = fg & 1;
        #pragma unroll
        for (int e = 0; e < 8; ++e)
            col_lds[ph][wave][(e >> 2) * 256 + 4 * lane + (e & 3)] = colacc[e];
        __syncthreads();
        for (int j = tid; j < SEQ; j += 256)
            colpart[((size_t)t * NF + f) * SEQ + j] =
                col_lds[ph][0][j] + col_lds[ph][1][j] + col_lds[ph][2][j] + col_lds[ph][3][j];
    }

    // flush WApart (write-once, float4 coalesced)
    float* __restrict__ wp = WApart + (size_t)g * SEQ * SEQ;
    #pragma unroll
    for (int rr = 0; rr < 4; ++rr) {
        const int i = row0 + rr;
        float4 o0 = make_float4(wa_acc[rr][0], wa_acc[rr][1], wa_acc[rr][2], wa_acc[rr][3]);
        float4 o1 = make_float4(wa_acc[rr][4], wa_acc[rr][5], wa_acc[rr][6], wa_acc[rr][7]);
        *(float4*)(wp + (size_t)i * SEQ + 4 * lane) = o0;
        *(float4*)(wp + (size_t)i * SEQ + 256 + 4 * lane) = o1;
    }
}

// ---------------- Pass WA-reduce: WA = sum_g WApart[g] ----------------
// 65536 float4 elements; grid 256 x block 256
__global__ __launch_bounds__(256) void wa_reduce_kernel(
    const float* __restrict__ WApart, float* __restrict__ WA)
{
    const size_t idx4 = (size_t)blockIdx.x * 256 + threadIdx.x;   // float4 index
    const float4* __restrict__ src = (const float4*)WApart;
    const size_t stride = (size_t)SEQ * SEQ / 4;                  // 65536
    float4 a = src[idx4];
    #pragma unroll 8
    for (int g = 1; g < NG; ++g) {
        float4 b = src[(size_t)g * stride + idx4];
        a.x += b.x; a.y += b.y; a.z += b.z; a.w += b.w;
    }
    ((float4*)WA)[idx4] = a;
}

// ---------------- Pass 2: per-head a1, a12, scale ----------------
// grid 660, block 512
__global__ __launch_bounds__(512) void pass2_kernel(
    const float* __restrict__ rowsum, const float* __restrict__ colpart,
    const int* __restrict__ tokens, const float* __restrict__ weight,
    float* __restrict__ a1, float* __restrict__ sfac)
{
    const int f = blockIdx.x;
    const int j = threadIdx.x;
    const int wave = j >> 6, lane = j & 63;

    float cs = 0.0f;
    #pragma unroll 8
    for (int t = 0; t < NT; ++t)
        cs += colpart[((size_t)t * NF + f) * SEQ + j];

    const float m = (j >= 1 && j <= SEQ - 2 && tokens[j] != EOSI) ? 1.0f : 0.0f;
    float v = m * (rowsum[(size_t)f * SEQ + j] + cs);
    a1[(size_t)f * SEQ + j] = v;

    float s = v;
    #pragma unroll
    for (int off = 32; off > 0; off >>= 1)
        s += __shfl_down(s, off, 64);
    __shared__ float part[8];
    if (lane == 0) part[wave] = s;
    __syncthreads();
    if (j == 0) {
        float a12 = 0.0f;
        #pragma unroll
        for (int k = 0; k < 8; ++k) a12 += part[k];
        sfac[f] = weight[f] / a12;
    }
}

// ---------------- Pass 3: rank-660 outer-product sum + WA + sigmoid ----------------
// grid (16,16), block 256; each block: 32x32 output tile; thread: 2x2 micro-tile
__global__ __launch_bounds__(256) void pass3_kernel(
    const float* __restrict__ WA, const float* __restrict__ a1,
    const float* __restrict__ sfac, const int* __restrict__ tokens,
    const float* __restrict__ bias, float* __restrict__ out)
{
    const int TI = blockIdx.y * 32;
    const int TJ = blockIdx.x * 32;
    const int tid = threadIdx.x;
    const int tx = tid & 15, ty = tid >> 4;

    __shared__ float u_s[16][33];
    __shared__ float v_s[16][33];

    float acc[2][2] = {{0.f, 0.f}, {0.f, 0.f}};

    for (int f0 = 0; f0 < NF; f0 += 16) {
        for (int e = tid; e < 512; e += 256) {
            const int ff = e >> 5, ii = e & 31;
            const int f = f0 + ff;
            int Iu = TI + 1 + ii; if (Iu > SEQ - 1) Iu = SEQ - 1;
            int Ju = TJ + 1 + ii; if (Ju > SEQ - 1) Ju = SEQ - 1;
            if (f < NF) {
                u_s[ff][ii] = a1[(size_t)f * SEQ + Iu] * sfac[f];
                v_s[ff][ii] = a1[(size_t)f * SEQ + Ju];
            } else {
                u_s[ff][ii] = 0.0f;
                v_s[ff][ii] = 0.0f;
            }
        }
        __syncthreads();
        #pragma unroll
        for (int ff = 0; ff < 16; ++ff) {
            const float u0 = u_s[ff][2 * ty],     u1 = u_s[ff][2 * ty + 1];
            const float w0 = v_s[ff][2 * tx],     w1 = v_s[ff][2 * tx + 1];
            acc[0][0] += u0 * w0; acc[0][1] += u0 * w1;
            acc[1][0] += u1 * w0; acc[1][1] += u1 * w1;
        }
        __syncthreads();
    }

    const float b = bias[0];
    #pragma unroll
    for (int dy = 0; dy < 2; ++dy) {
        #pragma unroll
        for (int dx = 0; dx < 2; ++dx) {
            const int i = TI + 2 * ty + dy;
            const int j = TJ + 2 * tx + dx;
            if (i < CROP && j < CROP) {
                const int I = i + 1, J = j + 1;
                const float mi = (tokens[I] != EOSI) ? 1.0f : 0.0f;
                const float mj = (tokens[J] != EOSI) ? 1.0f : 0.0f;
                const float first = mi * mj * (WA[(size_t)I * SEQ + J] + WA[(size_t)J * SEQ + I]);
                const float logit = first - acc[dy][dx] + b;
                out[(size_t)i * CROP + j] = 1.0f / (1.0f + expf(-logit));
            }
        }
    }
}

extern "C" void kernel_launch(void* const* d_in, const int* in_sizes, int n_in,
                              void* d_out, int out_size, void* d_ws, size_t ws_size,
                              hipStream_t stream) {
    const int*   tokens = (const int*)d_in[0];
    const float* A      = (const float*)d_in[1];
    const float* weight = (const float*)d_in[2];
    const float* bias   = (const float*)d_in[3];
    float* out = (float*)d_out;

    // workspace layout (floats), all write-once (no zeroing needed):
    // WApart[33*512*512] | colpart[32*660*512] | WA[512*512] | rowsum[660*512] | a1[660*512] | sfac[660]
    float* WApart  = (float*)d_ws;
    float* colpart = WApart + (size_t)NG * SEQ * SEQ;
    float* WA      = colpart + (size_t)NT * NF * SEQ;
    float* rowsum  = WA + (size_t)SEQ * SEQ;
    float* a1      = rowsum + (size_t)NF * SEQ;
    float* sfac    = a1 + (size_t)NF * SEQ;

    dim3 g1(NT, NG);   // 32 x 33
    pass1_kernel<<<g1, 256, 0, stream>>>(A, tokens, weight, WApart, rowsum, colpart);

    wa_reduce_kernel<<<256, 256, 0, stream>>>(WApart, WA);

    pass2_kernel<<<NF, 512, 0, stream>>>(rowsum, colpart, tokens, weight, a1, sfac);

    dim3 g3(16, 16);
    pass3_kernel<<<g3, 256, 0, stream>>>(WA, a1, sfac, tokens, bias, out);
}

// Round 3
// 227.648 us; speedup vs baseline: 1.5703x; 1.2442x over previous
//
#include <hip/hip_runtime.h>
#include <math.h>

// Problem constants (B=1, LAYERS=33, HEADS=20, SEQ=512)
#define SEQ   512
#define NF    660
#define CROP  510
#define EOSI  2
#define RT    16           // rows per block (pass1)
#define GH    20           // heads per group (pass1)
#define NT_   32           // row tiles
#define NG    33           // head groups

typedef float f4 __attribute__((ext_vector_type(4)));

__device__ __forceinline__ f4 ntl4(const float* p) {
    return __builtin_nontemporal_load((const f4*)p);
}

// ---------------- Pass 1: stream 692MB once, register-pipelined ----------------
// grid (32 row-tiles, 33 head-groups), block 256 (4 waves).
// Per wave: 4 rows, processed as 2 row-pairs; two 4xfloat4 register buffers
// ping-pong so one pair's loads are always in flight while computing the other.
// Col-sum combine batched over 2 heads -> 10 barriers (+1 initial) per block.

// load one row-pair (2 rows x 2 float4) of head f starting at absolute row prow
#define LOADP(buf, f, prow) do {                                              \
    const float* _b = A + ((size_t)(f) << 18) + ((size_t)(prow) << 9);        \
    buf[0] = ntl4(_b + 4 * lane);                                             \
    buf[1] = ntl4(_b + 256 + 4 * lane);                                       \
    buf[2] = ntl4(_b + 512 + 4 * lane);                                       \
    buf[3] = ntl4(_b + 768 + 4 * lane);                                       \
} while (0)

// consume one row-pair: wa += wf*v, cacc += mi*v, rowsum (POFF is 0 or 1, literal)
#define COMP(buf, wf, cacc, wa, POFF, f) do {                                 \
    _Pragma("unroll")                                                         \
    for (int rr = 0; rr < 2; ++rr) {                                          \
        const float mi = mrow[(POFF) * 2 + rr];                               \
        f4 x0 = buf[2 * rr], x1 = buf[2 * rr + 1];                            \
        float vals[8] = {x0[0], x0[1], x0[2], x0[3],                          \
                         x1[0], x1[1], x1[2], x1[3]};                         \
        float rs = 0.f;                                                       \
        _Pragma("unroll")                                                     \
        for (int e = 0; e < 8; ++e) {                                         \
            const float v = vals[e];                                          \
            wa[rr][e] += (wf) * v;                                            \
            rs += mskv[e] * v;                                                \
            cacc[e] += mi * v;                                                \
        }                                                                     \
        _Pragma("unroll")                                                     \
        for (int off = 32; off > 0; off >>= 1)                                \
            rs += __shfl_down(rs, off, 64);                                   \
        if (lane == 0)                                                        \
            rowsum[((size_t)(f) << 9) + row0 + (POFF) * 2 + rr] = rs;         \
    }                                                                         \
} while (0)

__global__ __launch_bounds__(256) void pass1_kernel(
    const float* __restrict__ A, const int* __restrict__ tokens,
    const float* __restrict__ weight,
    float* __restrict__ WApart, float* __restrict__ rowsum, float* __restrict__ colpart)
{
    __shared__ float msk[SEQ];
    __shared__ float col_lds[2][4][2][SEQ];   // [pingpong][wave][head-in-pair][col]

    const int t = blockIdx.x, g = blockIdx.y;
    const int tid = threadIdx.x, wave = tid >> 6, lane = tid & 63;

    for (int j = tid; j < SEQ; j += 256)
        msk[j] = (j >= 1 && j <= SEQ - 2 && tokens[j] != EOSI) ? 1.f : 0.f;
    __syncthreads();

    float mskv[8];
    #pragma unroll
    for (int e = 0; e < 8; ++e)
        mskv[e] = msk[(e >> 2) * 256 + 4 * lane + (e & 3)];

    const int row0 = t * RT + wave * 4;
    const float mrow[4] = {msk[row0], msk[row0 + 1], msk[row0 + 2], msk[row0 + 3]};

    float waLo[2][8], waHi[2][8];   // rows row0..row0+1 / row0+2..row0+3
    #pragma unroll
    for (int r = 0; r < 2; ++r)
        #pragma unroll
        for (int e = 0; e < 8; ++e) { waLo[r][e] = 0.f; waHi[r][e] = 0.f; }

    f4 bufA[4], bufB[4];
    const int fbase = g * GH;
    LOADP(bufA, fbase, row0);               // prime the pipeline

    for (int hp = 0; hp < 10; ++hp) {
        const int f0 = fbase + 2 * hp, f1 = f0 + 1;
        const float wf0 = weight[f0], wf1 = weight[f1];
        float caccA[8] = {0, 0, 0, 0, 0, 0, 0, 0};
        float caccB[8] = {0, 0, 0, 0, 0, 0, 0, 0};

        LOADP(bufB, f0, row0 + 2);          // (f0, pair1)
        COMP(bufA, wf0, caccA, waLo, 0, f0);
        LOADP(bufA, f1, row0);              // (f1, pair0)
        COMP(bufB, wf0, caccA, waHi, 1, f0);
        LOADP(bufB, f1, row0 + 2);          // (f1, pair1)
        COMP(bufA, wf1, caccB, waLo, 0, f1);
        if (hp < 9) LOADP(bufA, f0 + 2, row0);   // next head-pair (pair0)
        COMP(bufB, wf1, caccB, waHi, 1, f1);

        // cross-wave col-sum combine for heads f0,f1 (ping-pong, 1 barrier)
        const int pp = hp & 1;
        #pragma unroll
        for (int e = 0; e < 8; ++e) {
            const int c = (e >> 2) * 256 + 4 * lane + (e & 3);
            col_lds[pp][wave][0][c] = caccA[e];
            col_lds[pp][wave][1][c] = caccB[e];
        }
        __syncthreads();
        #pragma unroll
        for (int jj = 0; jj < 4; ++jj) {
            const int j = jj * 256 + tid;         // 0..1023 over 2 heads
            const int h = j >> 9, c = j & 511;
            const float s = col_lds[pp][0][h][c] + col_lds[pp][1][h][c]
                          + col_lds[pp][2][h][c] + col_lds[pp][3][h][c];
            colpart[((size_t)t * NF + f0 + h) * SEQ + c] = s;
        }
    }

    // flush WApart (write-once, float4 coalesced)
    float* __restrict__ wp = WApart + (size_t)g * SEQ * SEQ;
    #pragma unroll
    for (int rr = 0; rr < 2; ++rr) {
        f4 l0 = {waLo[rr][0], waLo[rr][1], waLo[rr][2], waLo[rr][3]};
        f4 l1 = {waLo[rr][4], waLo[rr][5], waLo[rr][6], waLo[rr][7]};
        *(f4*)(wp + ((size_t)(row0 + rr) << 9) + 4 * lane) = l0;
        *(f4*)(wp + ((size_t)(row0 + rr) << 9) + 256 + 4 * lane) = l1;
        f4 h0 = {waHi[rr][0], waHi[rr][1], waHi[rr][2], waHi[rr][3]};
        f4 h1 = {waHi[rr][4], waHi[rr][5], waHi[rr][6], waHi[rr][7]};
        *(f4*)(wp + ((size_t)(row0 + 2 + rr) << 9) + 4 * lane) = h0;
        *(f4*)(wp + ((size_t)(row0 + 2 + rr) << 9) + 256 + 4 * lane) = h1;
    }
}

// ---------------- Kernel 2 (merged): WA-reduce + per-head a1/a12/scale --------
// grid 128+660 blocks x 512 threads. Blocks [0,128): WA = sum_g WApart[g].
// Blocks [128,788): head f = b-128: a1, a12, sfac.
__global__ __launch_bounds__(512) void kernel2(
    const float* __restrict__ WApart, float* __restrict__ WA,
    const float* __restrict__ rowsum, const float* __restrict__ colpart,
    const int* __restrict__ tokens, const float* __restrict__ weight,
    float* __restrict__ a1, float* __restrict__ sfac)
{
    __shared__ float part[8];
    const int b = blockIdx.x, tid = threadIdx.x;
    if (b < 128) {
        const size_t idx4 = (size_t)b * 512 + tid;     // float4 index, 65536 total
        f4 a = ntl4(WApart + 4 * idx4);
        #pragma unroll
        for (int g = 1; g < NG; ++g) {
            f4 x = ntl4(WApart + (size_t)g * (SEQ * SEQ) + 4 * idx4);
            a += x;
        }
        *(f4*)(WA + 4 * idx4) = a;
    } else {
        const int f = b - 128, j = tid;
        float cs = 0.f;
        #pragma unroll
        for (int t = 0; t < NT_; ++t)
            cs += colpart[((size_t)t * NF + f) * SEQ + j];
        const float m = (j >= 1 && j <= SEQ - 2 && tokens[j] != EOSI) ? 1.f : 0.f;
        const float v = m * (rowsum[((size_t)f << 9) + j] + cs);
        a1[((size_t)f << 9) + j] = v;
        float s = v;
        #pragma unroll
        for (int off = 32; off > 0; off >>= 1)
            s += __shfl_down(s, off, 64);
        const int wave = tid >> 6, lane = tid & 63;
        if (lane == 0) part[wave] = s;
        __syncthreads();
        if (tid == 0) {
            float a12 = 0.f;
            #pragma unroll
            for (int k = 0; k < 8; ++k) a12 += part[k];
            sfac[f] = weight[f] / a12;
        }
    }
}

// ---------------- Pass 3: rank-660 outer-product + WA + sigmoid ----------------
__global__ __launch_bounds__(256) void pass3_kernel(
    const float* __restrict__ WA, const float* __restrict__ a1,
    const float* __restrict__ sfac, const int* __restrict__ tokens,
    const float* __restrict__ bias, float* __restrict__ out)
{
    const int TI = blockIdx.y * 32;
    const int TJ = blockIdx.x * 32;
    const int tid = threadIdx.x;
    const int tx = tid & 15, ty = tid >> 4;

    __shared__ float u_s[16][33];
    __shared__ float v_s[16][33];

    float acc[2][2] = {{0.f, 0.f}, {0.f, 0.f}};

    for (int f0 = 0; f0 < NF; f0 += 16) {
        for (int e = tid; e < 512; e += 256) {
            const int ff = e >> 5, ii = e & 31;
            const int f = f0 + ff;
            int Iu = TI + 1 + ii; if (Iu > SEQ - 1) Iu = SEQ - 1;
            int Ju = TJ + 1 + ii; if (Ju > SEQ - 1) Ju = SEQ - 1;
            if (f < NF) {
                u_s[ff][ii] = a1[(size_t)f * SEQ + Iu] * sfac[f];
                v_s[ff][ii] = a1[(size_t)f * SEQ + Ju];
            } else {
                u_s[ff][ii] = 0.0f;
                v_s[ff][ii] = 0.0f;
            }
        }
        __syncthreads();
        #pragma unroll
        for (int ff = 0; ff < 16; ++ff) {
            const float u0 = u_s[ff][2 * ty],     u1 = u_s[ff][2 * ty + 1];
            const float w0 = v_s[ff][2 * tx],     w1 = v_s[ff][2 * tx + 1];
            acc[0][0] += u0 * w0; acc[0][1] += u0 * w1;
            acc[1][0] += u1 * w0; acc[1][1] += u1 * w1;
        }
        __syncthreads();
    }

    const float b = bias[0];
    #pragma unroll
    for (int dy = 0; dy < 2; ++dy) {
        #pragma unroll
        for (int dx = 0; dx < 2; ++dx) {
            const int i = TI + 2 * ty + dy;
            const int j = TJ + 2 * tx + dx;
            if (i < CROP && j < CROP) {
                const int I = i + 1, J = j + 1;
                const float mi = (tokens[I] != EOSI) ? 1.0f : 0.0f;
                const float mj = (tokens[J] != EOSI) ? 1.0f : 0.0f;
                const float first = mi * mj * (WA[(size_t)I * SEQ + J] + WA[(size_t)J * SEQ + I]);
                const float logit = first - acc[dy][dx] + b;
                out[(size_t)i * CROP + j] = 1.0f / (1.0f + expf(-logit));
            }
        }
    }
}

extern "C" void kernel_launch(void* const* d_in, const int* in_sizes, int n_in,
                              void* d_out, int out_size, void* d_ws, size_t ws_size,
                              hipStream_t stream) {
    const int*   tokens = (const int*)d_in[0];
    const float* A      = (const float*)d_in[1];
    const float* weight = (const float*)d_in[2];
    const float* bias   = (const float*)d_in[3];
    float* out = (float*)d_out;

    // workspace (floats), all write-once, no zeroing:
    // WApart[33*512*512] | colpart[32*660*512] | WA[512*512] | rowsum[660*512] | a1[660*512] | sfac[660]
    float* WApart  = (float*)d_ws;
    float* colpart = WApart + (size_t)NG * SEQ * SEQ;
    float* WA      = colpart + (size_t)NT_ * NF * SEQ;
    float* rowsum  = WA + (size_t)SEQ * SEQ;
    float* a1      = rowsum + (size_t)NF * SEQ;
    float* sfac    = a1 + (size_t)NF * SEQ;

    dim3 g1(NT_, NG);   // 32 x 33
    pass1_kernel<<<g1, 256, 0, stream>>>(A, tokens, weight, WApart, rowsum, colpart);

    kernel2<<<128 + NF, 512, 0, stream>>>(WApart, WA, rowsum, colpart, tokens, weight, a1, sfac);

    dim3 g3(16, 16);
    pass3_kernel<<<g3, 256, 0, stream>>>(WA, a1, sfac, tokens, bias, out);
}